// Round 12
// baseline (259.717 us; speedup 1.0000x reference)
//
#include <hip/hip_runtime.h>
#include <hip/hip_bf16.h>
#include <stdint.h>
#include <type_traits>

// ---------------------------------------------------------------------------
// GCN on MI355X: 3x (dense GEMM -> spmm -> bias [-> relu -> concat])
// fp16 activations/weights, fp32 accumulation everywhere.
// R20: R17 structure restored (R19 batching regressed: serialized 8 chains/
//      wave + lost XCD pinning). Split-phase 8-deep gather RETRIED with
//      __launch_bounds__(256,4): R18's failure was the compiler's 56-VGPR
//      occupancy cap serializing the gathers; bounds(256,4) allows 128 VGPR
//      (16 waves/CU >= measured 10). Fast path = 8 ev broadcasts then 8
//      independent 16B gathers in flight. Per-lane accumulation order
//      unchanged. GEMMs identical to R17 (234.1 us best).
// ---------------------------------------------------------------------------

typedef _Float16 half8 __attribute__((ext_vector_type(8)));
typedef _Float16 half4 __attribute__((ext_vector_type(4)));
typedef float    f32x4 __attribute__((ext_vector_type(4)));

#define N_NODES 10000
#define M_PAD   10112   // 158 * 64
#define N_EDGES 320000
#define ROWCAP  96      // max edges/row; Poisson(32) => P(>96) ~ 1e-19

__device__ __forceinline__ void async16(const void* g, void* l) {
    __builtin_amdgcn_global_load_lds(
        (const __attribute__((address_space(1))) void*)g,
        (__attribute__((address_space(3))) void*)l, 16, 0, 0);
}

// Sliced store index for S: [col/128][row][col%128]
__device__ __forceinline__ size_t sidx(int row, int col) {
    return ((size_t)(col >> 7) * M_PAD + row) * 128 + (col & 127);
}

// ---------------------------------------------------------------------------
// GEMM body: S_sliced = A[M_PAD x K] * Bt[Nc x K]^T. fp16 in/out, fp32 acc.
// Tile TM x TN, BK=32, 4 waves 2x2, double-buffered LDS, async16 staging.
// (R5/R7-proven; C-store sliced.)
// ---------------------------------------------------------------------------
template <int TM, int TN>
__device__ __forceinline__ void gemm_body(
    int bx, int by,
    const _Float16* __restrict__ A,
    const _Float16* __restrict__ Bt,
    _Float16* __restrict__ C,
    int K, int Nc)
{
    constexpr int WM = TM / 2;
    constexpr int WN = TN / 2;
    constexpr int MT = WM / 16;
    constexpr int NT = WN / 16;
    constexpr int NCHUNK = (TM + TN) / 16;
    constexpr int CA = TM / 16;

    __shared__ _Float16 As[2][TM * 32];
    __shared__ _Float16 Bs[2][TN * 32];

    const int t    = threadIdx.x;
    const int lane = t & 63;
    const int wid  = t >> 6;
    const int wrow = wid >> 1;
    const int wcol = wid & 1;
    const int quad = lane >> 4;
    const int l15  = lane & 15;

    const int rowBase = by * TM;
    const int colBase = bx * TN;

    const int rIn = lane >> 2;
    const int cIn = (lane & 3) * 8;

    f32x4 acc[MT][NT];
#pragma unroll
    for (int m = 0; m < MT; ++m)
#pragma unroll
        for (int n = 0; n < NT; ++n)
            acc[m][n] = (f32x4){0.f, 0.f, 0.f, 0.f};

    auto stage = [&](int buf, int k0) {
#pragma unroll
        for (int p = 0; p < NCHUNK / 4; ++p) {
            const int c = wid + p * 4;
            if (c < CA) {
                const int r = c * 16 + rIn;
                async16(&A[(size_t)(rowBase + r) * K + k0 + cIn], &As[buf][c * 512]);
            } else {
                const int r = (c - CA) * 16 + rIn;
                async16(&Bt[(size_t)(colBase + r) * K + k0 + cIn], &Bs[buf][(c - CA) * 512]);
            }
        }
    };

    const int nk = K >> 5;
    stage(0, 0);

    for (int i = 0; i < nk; ++i) {
        __syncthreads();
        if (i + 1 < nk) stage((i + 1) & 1, (i + 1) << 5);

        const int b = i & 1;
        half8 af[MT], bf[NT];
#pragma unroll
        for (int m = 0; m < MT; ++m)
            af[m] = *(const half8*)(&As[b][(wrow * WM + m * 16 + l15) * 32 + quad * 8]);
#pragma unroll
        for (int n = 0; n < NT; ++n)
            bf[n] = *(const half8*)(&Bs[b][(wcol * WN + n * 16 + l15) * 32 + quad * 8]);

#pragma unroll
        for (int m = 0; m < MT; ++m)
#pragma unroll
            for (int n = 0; n < NT; ++n)
                acc[m][n] = __builtin_amdgcn_mfma_f32_16x16x32_f16(
                    af[m], bf[n], acc[m][n], 0, 0, 0);
    }

#pragma unroll
    for (int m = 0; m < MT; ++m) {
#pragma unroll
        for (int n = 0; n < NT; ++n) {
            int col = colBase + wcol * WN + n * 16 + l15;
#pragma unroll
            for (int r = 0; r < 4; ++r) {
                int row = rowBase + wrow * WM + m * 16 + quad * 4 + r;
                C[sidx(row, col)] = (_Float16)acc[m][n][r];
            }
        }
    }
}

template <int TM, int TN>
__global__ __launch_bounds__(256) void gemm_f16_t(
    const _Float16* __restrict__ A,
    const _Float16* __restrict__ Bt,
    _Float16* __restrict__ C,
    int K, int Nc)
{
    gemm_body<TM, TN>(blockIdx.x, blockIdx.y, A, Bt, C, K, Nc);
}

// ---------------------------------------------------------------------------
// Dual-relu GEMM body (R15-proven): S_sliced = relu(Z)@Wtop + Z@Wbot.
// Bt=[Nc x 1024] (top half k<512, bottom k>=512), Z=[M_PAD x 512] row-major.
// ---------------------------------------------------------------------------
template <int TM, int TN>
__device__ __forceinline__ void gemm_dual(
    int bx, int by,
    const _Float16* __restrict__ Z,     // [M_PAD x 512]
    const _Float16* __restrict__ Bt,    // [Nc x 1024]
    _Float16* __restrict__ C,           // S sliced
    int Nc)
{
    constexpr int WM = TM / 2;
    constexpr int WN = TN / 2;
    constexpr int MT = WM / 16;
    constexpr int NT = WN / 16;
    constexpr int CA = TM / 16;
    constexpr int CB = TN / 16;
    constexpr int NCH = CA + 2 * CB;    // A + Btop + Bbot chunks

    __shared__ _Float16 As [2][TM * 32];
    __shared__ _Float16 Bs0[2][TN * 32];
    __shared__ _Float16 Bs1[2][TN * 32];

    const int t    = threadIdx.x;
    const int lane = t & 63;
    const int wid  = t >> 6;
    const int wrow = wid >> 1;
    const int wcol = wid & 1;
    const int quad = lane >> 4;
    const int l15  = lane & 15;

    const int rowBase = by * TM;
    const int colBase = bx * TN;

    const int rIn = lane >> 2;
    const int cIn = (lane & 3) * 8;

    f32x4 acc[MT][NT];
#pragma unroll
    for (int m = 0; m < MT; ++m)
#pragma unroll
        for (int n = 0; n < NT; ++n)
            acc[m][n] = (f32x4){0.f, 0.f, 0.f, 0.f};

    auto stage = [&](int buf, int k0) {
#pragma unroll
        for (int p = 0; p < NCH / 4; ++p) {
            const int c = wid + p * 4;
            if (c < CA) {
                const int r = c * 16 + rIn;
                async16(&Z[(size_t)(rowBase + r) * 512 + k0 + cIn], &As[buf][c * 512]);
            } else if (c < CA + CB) {
                const int cc = c - CA;
                const int r = cc * 16 + rIn;
                async16(&Bt[(size_t)(colBase + r) * 1024 + k0 + cIn], &Bs0[buf][cc * 512]);
            } else {
                const int cc = c - CA - CB;
                const int r = cc * 16 + rIn;
                async16(&Bt[(size_t)(colBase + r) * 1024 + 512 + k0 + cIn], &Bs1[buf][cc * 512]);
            }
        }
    };

    stage(0, 0);

    for (int i = 0; i < 16; ++i) {      // K=512 in steps of 32
        __syncthreads();
        if (i + 1 < 16) stage((i + 1) & 1, (i + 1) << 5);

        const int b = i & 1;
        half8 af[MT], ar[MT], bf0[NT], bf1[NT];
#pragma unroll
        for (int m = 0; m < MT; ++m) {
            af[m] = *(const half8*)(&As[b][(wrow * WM + m * 16 + l15) * 32 + quad * 8]);
#pragma unroll
            for (int j = 0; j < 8; ++j)
                ar[m][j] = af[m][j] > (_Float16)0 ? af[m][j] : (_Float16)0;
        }
#pragma unroll
        for (int n = 0; n < NT; ++n) {
            bf0[n] = *(const half8*)(&Bs0[b][(wcol * WN + n * 16 + l15) * 32 + quad * 8]);
            bf1[n] = *(const half8*)(&Bs1[b][(wcol * WN + n * 16 + l15) * 32 + quad * 8]);
        }

#pragma unroll
        for (int m = 0; m < MT; ++m)
#pragma unroll
            for (int n = 0; n < NT; ++n) {
                acc[m][n] = __builtin_amdgcn_mfma_f32_16x16x32_f16(
                    ar[m], bf0[n], acc[m][n], 0, 0, 0);
                acc[m][n] = __builtin_amdgcn_mfma_f32_16x16x32_f16(
                    af[m], bf1[n], acc[m][n], 0, 0, 0);
            }
    }

#pragma unroll
    for (int m = 0; m < MT; ++m) {
#pragma unroll
        for (int n = 0; n < NT; ++n) {
            int col = colBase + wcol * WN + n * 16 + l15;
#pragma unroll
            for (int r = 0; r < 4; ++r) {
                int row = rowBase + wrow * WM + m * 16 + quad * 4 + r;
                C[sidx(row, col)] = (_Float16)acc[m][n][r];
            }
        }
    }
}

template <int TM, int TN>
__global__ __launch_bounds__(256) void gemm_dual_k(
    const _Float16* __restrict__ Z,
    const _Float16* __restrict__ Bt,
    _Float16* __restrict__ C,
    int Nc)
{
    gemm_dual<TM, TN>(blockIdx.x, blockIdx.y, Z, Bt, C, Nc);
}

// ---------------------------------------------------------------------------
// prep + edge-scatter fused (R16-proven): scatter blocks first (latency-
// bound, hide under BW-bound converts); slot = atomicAdd(counts[row]) is
// the scatter address. Then x fp32->fp16 and LDS-tiled W transposes.
// ---------------------------------------------------------------------------
#define SCAT_B    1250   // 320000 / 256
#define PREP_XB   5000
#define PREP_W0B  256    // 512x512  : 16x16 tiles of 32x32
#define PREP_W1B  512    // 1024x512 : 32x16
#define PREP_W2B  256    // 1024x256 : 32x8
#define PREPH_BLKS (SCAT_B + PREP_XB + PREP_W0B + PREP_W1B + PREP_W2B)

__device__ __forceinline__ void tile_tr(const float* __restrict__ W,
                                        _Float16* __restrict__ Wt,
                                        int K, int Nc, int tR, int tC, int t) {
    __shared__ float tile[32][33];
    const int ty = t >> 5, tx = t & 31;
#pragma unroll
    for (int it = 0; it < 4; ++it)
        tile[ty + 8 * it][tx] = W[(size_t)(tR * 32 + ty + 8 * it) * Nc + tC * 32 + tx];
    __syncthreads();
#pragma unroll
    for (int it = 0; it < 4; ++it)
        Wt[(size_t)(tC * 32 + ty + 8 * it) * K + tR * 32 + tx] =
            (_Float16)tile[tx][ty + 8 * it];
}

__global__ __launch_bounds__(256) void prep_scatter(
    const float* __restrict__ x,  _Float16* __restrict__ Xh,
    const float* __restrict__ W0, _Float16* __restrict__ W0t,
    const float* __restrict__ W1, _Float16* __restrict__ W1t,
    const float* __restrict__ W2, _Float16* __restrict__ W2t,
    const int* __restrict__ edge_row, const int* __restrict__ edge_col,
    const float* __restrict__ edge_val,
    int* __restrict__ counts, float2* __restrict__ ev) {
    const int t = threadIdx.x;
    int b = blockIdx.x;
    if (b < SCAT_B) {
        int i = b * 256 + t;
        if (i < N_EDGES) {
            int r = edge_row[i];
            int slot = atomicAdd(&counts[r], 1);
            if (slot < ROWCAP)   // OOB guard; never taken for Poisson(32)
                ev[(size_t)r * ROWCAP + slot] =
                    make_float2(__int_as_float(edge_col[i]), edge_val[i]);
        }
        return;
    }
    b -= SCAT_B;
    if (b < PREP_XB) {
        int i = b * 256 + t;                 // exactly 10000*512/4 threads
        f32x4 v = *(const f32x4*)(x + (size_t)i * 4);
        half4 h;
        h[0] = (_Float16)v[0]; h[1] = (_Float16)v[1];
        h[2] = (_Float16)v[2]; h[3] = (_Float16)v[3];
        *(half4*)(Xh + (size_t)i * 4) = h;
        return;
    }
    b -= PREP_XB;
    if (b < PREP_W0B) { tile_tr(W0, W0t, 512, 512, b >> 4, b & 15, t); return; }
    b -= PREP_W0B;
    if (b < PREP_W1B) { tile_tr(W1, W1t, 1024, 512, b >> 4, b & 15, t); return; }
    b -= PREP_W1B;
    { tile_tr(W2, W2t, 1024, 256, b >> 3, b & 7, t); }
}

// ---------------------------------------------------------------------------
// SpMM, feature-sliced, slice-major S + XCD-pinned slices (R17 grid) +
// split-phase gather with __launch_bounds__(256,4) (128-VGPR budget):
// fast path = 8 ev broadcasts, then 8 independent 16B gathers in flight,
// then 64 FMAs. Mean row (8 edges/group) = one fast iteration. Per-lane
// accumulation order identical to R17.
// ---------------------------------------------------------------------------
template <int D, bool FINAL>
__global__ __launch_bounds__(256, 4) void spmm_slice(
    const int* __restrict__ counts,
    const float2* __restrict__ ev,
    const _Float16* __restrict__ S,     // sliced: [D/128][M_PAD][128]
    const float* __restrict__ bias,     // [D]
    _Float16* __restrict__ Zout,        // [M_PAD x D] if !FINAL
    float* __restrict__ Fout)           // [N_NODES x D] if FINAL
{
    constexpr int NS  = D / 128;        // slices
    constexpr int XPS = 8 / NS;         // XCDs per slice
    const int bid = blockIdx.x;
    const int s   = (bid & 7) / XPS;                      // slice -> XCD group
    const int rq  = (bid >> 3) * XPS + (bid & (XPS - 1)); // row-quad
    const int w  = threadIdx.x >> 6;    // wave -> row within quad
    const int row = rq * 4 + w;
    const int lane = threadIdx.x & 63;
    const int g = lane >> 4;            // edge-group 0..3
    const int l = lane & 15;            // feature-lane

    const int r0 = row * ROWCAP;
    const int r1 = r0 + counts[row];

    float acc[8];
#pragma unroll
    for (int j = 0; j < 8; ++j) acc[j] = 0.f;

    const _Float16* __restrict__ Sb = S + (size_t)s * M_PAD * 128 + l * 8;

    int e = r0 + g;
    // fast path: 8 edges/group (one mean row) -- ev chain paid once,
    // 8 independent gathers in flight (needs the 128-VGPR budget)
    for (; e + 28 < r1; e += 32) {
        float2 p[8];
        half8  v[8];
#pragma unroll
        for (int u = 0; u < 8; ++u) p[u] = ev[e + 4 * u];
#pragma unroll
        for (int u = 0; u < 8; ++u)
            v[u] = *(const half8*)(Sb + (size_t)__float_as_int(p[u].x) * 128);
#pragma unroll
        for (int u = 0; u < 8; ++u)
#pragma unroll
            for (int j = 0; j < 8; ++j) acc[j] += p[u].y * (float)v[u][j];
    }
    // tail: unroll 4 (4 gathers in flight)
    for (; e + 12 < r1; e += 16) {
        float2 p[4];
        half8  v[4];
#pragma unroll
        for (int u = 0; u < 4; ++u) p[u] = ev[e + 4 * u];
#pragma unroll
        for (int u = 0; u < 4; ++u)
            v[u] = *(const half8*)(Sb + (size_t)__float_as_int(p[u].x) * 128);
#pragma unroll
        for (int u = 0; u < 4; ++u)
#pragma unroll
            for (int j = 0; j < 8; ++j) acc[j] += p[u].y * (float)v[u][j];
    }
    for (; e + 4 < r1; e += 8) {
        float2 p0 = ev[e];
        float2 p1 = ev[e + 4];
        half8 v0 = *(const half8*)(Sb + (size_t)__float_as_int(p0.x) * 128);
        half8 v1 = *(const half8*)(Sb + (size_t)__float_as_int(p1.x) * 128);
#pragma unroll
        for (int j = 0; j < 8; ++j) {
            acc[j] += p0.y * (float)v0[j];
            acc[j] += p1.y * (float)v1[j];
        }
    }
    if (e < r1) {
        float2 p0 = ev[e];
        half8 v0 = *(const half8*)(Sb + (size_t)__float_as_int(p0.x) * 128);
#pragma unroll
        for (int j = 0; j < 8; ++j) acc[j] += p0.y * (float)v0[j];
    }

    // butterfly across the 4 edge-groups (lanes xor 16, xor 32)
#pragma unroll
    for (int j = 0; j < 8; ++j) {
        acc[j] += __shfl_xor(acc[j], 16, 64);
        acc[j] += __shfl_xor(acc[j], 32, 64);
    }

    const int f0 = s * 128 + l * 8;
    f32x4 b0 = *(const f32x4*)(bias + f0);
    f32x4 b1 = *(const f32x4*)(bias + f0 + 4);

    if constexpr (FINAL) {
        if (g == 0) {
            f32x4 o = {acc[0] + b0[0], acc[1] + b0[1], acc[2] + b0[2], acc[3] + b0[3]};
            *(f32x4*)(Fout + (size_t)row * D + f0) = o;
        } else if (g == 1) {
            f32x4 o = {acc[4] + b1[0], acc[5] + b1[1], acc[6] + b1[2], acc[7] + b1[3]};
            *(f32x4*)(Fout + (size_t)row * D + f0 + 4) = o;
        }
    } else {
        if (g == 0) {                   // single fp16 store of x_ (pre-relu)
            half8 h;
#pragma unroll
            for (int j = 0; j < 4; ++j) h[j] = (_Float16)(acc[j] + b0[j]);
#pragma unroll
            for (int j = 0; j < 4; ++j) h[4 + j] = (_Float16)(acc[4 + j] + b1[j]);
            *(half8*)(Zout + (size_t)row * D + f0) = h;
        }
    }
}

// ---------------------------------------------------------------------------
static inline char* alignp(char* p, size_t a) {
    return (char*)(((uintptr_t)p + a - 1) & ~(uintptr_t)(a - 1));
}

extern "C" void kernel_launch(void* const* d_in, const int* in_sizes, int n_in,
                              void* d_out, int out_size, void* d_ws, size_t ws_size,
                              hipStream_t stream) {
    const float* x        = (const float*)d_in[0];   // [10000 x 512]
    const int*   edge_row = (const int*)d_in[1];     // [E]
    const int*   edge_col = (const int*)d_in[2];     // [E]
    const float* edge_val = (const float*)d_in[3];   // [E]
    const float* W0 = (const float*)d_in[4];         // [512 x 512]
    const float* W1 = (const float*)d_in[5];         // [1024 x 512]
    const float* W2 = (const float*)d_in[6];         // [1024 x 256]
    const float* b0 = (const float*)d_in[7];
    const float* b1 = (const float*)d_in[8];
    const float* b2 = (const float*)d_in[9];
    float* out = (float*)d_out;                      // [10000 x 256]

    // ---- workspace carve-up ----
    char* p = (char*)d_ws;
    _Float16* Xh  = (_Float16*)alignp(p, 256);  p = (char*)(Xh  + (size_t)M_PAD * 512);
    _Float16* S   = (_Float16*)alignp(p, 256);  p = (char*)(S   + (size_t)M_PAD * 512);
    _Float16* Z   = (_Float16*)alignp(p, 256);  p = (char*)(Z   + (size_t)M_PAD * 512);
    _Float16* W0t = (_Float16*)alignp(p, 256);  p = (char*)(W0t + (size_t)512 * 512);
    _Float16* W1t = (_Float16*)alignp(p, 256);  p = (char*)(W1t + (size_t)512 * 1024);
    _Float16* W2t = (_Float16*)alignp(p, 256);  p = (char*)(W2t + (size_t)256 * 1024);
    int*    counts  = (int*)alignp(p, 256);     p = (char*)(counts + N_NODES);
    float2* ev      = (float2*)alignp(p, 256);  p = (char*)(ev + (size_t)N_NODES * ROWCAP);

    // ---- zero counts (graph memset node), then prep+scatter fused ----
    (void)hipMemsetAsync(counts, 0, N_NODES * sizeof(int), stream);
    prep_scatter<<<PREPH_BLKS, 256, 0, stream>>>(x, Xh, W0, W0t, W1, W1t, W2, W2t,
                                                 edge_row, edge_col, edge_val,
                                                 counts, ev);

    // ---- layer 0: GEMM (64x128) -> sliced S ----
    gemm_f16_t<64, 128><<<dim3(4, M_PAD / 64), 256, 0, stream>>>(Xh, W0t, S, 512, 512);
    spmm_slice<512, false><<<(N_NODES / 4) * 4, 256, 0, stream>>>(counts, ev, S, b0, Z, nullptr);
    // ---- layer 1: dual-relu GEMM on Z -> sliced S ----
    gemm_dual_k<64, 128><<<dim3(4, M_PAD / 64), 256, 0, stream>>>(Z, W1t, S, 512);
    spmm_slice<512, false><<<(N_NODES / 4) * 4, 256, 0, stream>>>(counts, ev, S, b1, Z, nullptr);
    // ---- layer 2: dual-relu GEMM, Nc=256 -> sliced S ----
    gemm_dual_k<64, 64><<<dim3(4, M_PAD / 64), 256, 0, stream>>>(Z, W2t, S, 256);
    spmm_slice<256, true><<<(N_NODES / 4) * 2, 256, 0, stream>>>(counts, ev, S, b2, nullptr, out);
}

// Round 13
// 224.836 us; speedup vs baseline: 1.1551x; 1.1551x over previous
//
#include <hip/hip_runtime.h>
#include <hip/hip_bf16.h>
#include <stdint.h>
#include <type_traits>

// ---------------------------------------------------------------------------
// GCN on MI355X: 3x (dense GEMM -> spmm -> bias [-> relu -> concat])
// fp16 activations/weights, fp32 accumulation everywhere.
// R21: R17-exact structure (8-deep gather dead: VGPR stayed 56 under
//      bounds(256,4), regressed twice). NEW: packed ev = 4B/edge
//      (col:u16 | val:fp16<<16). ev 7.68->3.84 MB, so slice-pinned
//      working set 10.3->6.4 MB fits the XCD-pair L2 (8 MB) -> the
//      ev->S chained loads become L2-resident instead of L3.
//      Inner loops otherwise byte-identical to R17 (234.1 us best).
// ---------------------------------------------------------------------------

typedef _Float16 half8 __attribute__((ext_vector_type(8)));
typedef _Float16 half4 __attribute__((ext_vector_type(4)));
typedef float    f32x4 __attribute__((ext_vector_type(4)));

#define N_NODES 10000
#define M_PAD   10112   // 158 * 64
#define N_EDGES 320000
#define ROWCAP  96      // max edges/row; Poisson(32) => P(>96) ~ 1e-19

__device__ __forceinline__ void async16(const void* g, void* l) {
    __builtin_amdgcn_global_load_lds(
        (const __attribute__((address_space(1))) void*)g,
        (__attribute__((address_space(3))) void*)l, 16, 0, 0);
}

// Sliced store index for S: [col/128][row][col%128]
__device__ __forceinline__ size_t sidx(int row, int col) {
    return ((size_t)(col >> 7) * M_PAD + row) * 128 + (col & 127);
}

__device__ __forceinline__ float unpack_val(unsigned pe) {
    unsigned short hb = (unsigned short)(pe >> 16);
    _Float16 hv;
    __builtin_memcpy(&hv, &hb, 2);
    return (float)hv;
}

// ---------------------------------------------------------------------------
// GEMM body: S_sliced = A[M_PAD x K] * Bt[Nc x K]^T. fp16 in/out, fp32 acc.
// Tile TM x TN, BK=32, 4 waves 2x2, double-buffered LDS, async16 staging.
// (R5/R7-proven; C-store sliced.)
// ---------------------------------------------------------------------------
template <int TM, int TN>
__device__ __forceinline__ void gemm_body(
    int bx, int by,
    const _Float16* __restrict__ A,
    const _Float16* __restrict__ Bt,
    _Float16* __restrict__ C,
    int K, int Nc)
{
    constexpr int WM = TM / 2;
    constexpr int WN = TN / 2;
    constexpr int MT = WM / 16;
    constexpr int NT = WN / 16;
    constexpr int NCHUNK = (TM + TN) / 16;
    constexpr int CA = TM / 16;

    __shared__ _Float16 As[2][TM * 32];
    __shared__ _Float16 Bs[2][TN * 32];

    const int t    = threadIdx.x;
    const int lane = t & 63;
    const int wid  = t >> 6;
    const int wrow = wid >> 1;
    const int wcol = wid & 1;
    const int quad = lane >> 4;
    const int l15  = lane & 15;

    const int rowBase = by * TM;
    const int colBase = bx * TN;

    const int rIn = lane >> 2;
    const int cIn = (lane & 3) * 8;

    f32x4 acc[MT][NT];
#pragma unroll
    for (int m = 0; m < MT; ++m)
#pragma unroll
        for (int n = 0; n < NT; ++n)
            acc[m][n] = (f32x4){0.f, 0.f, 0.f, 0.f};

    auto stage = [&](int buf, int k0) {
#pragma unroll
        for (int p = 0; p < NCHUNK / 4; ++p) {
            const int c = wid + p * 4;
            if (c < CA) {
                const int r = c * 16 + rIn;
                async16(&A[(size_t)(rowBase + r) * K + k0 + cIn], &As[buf][c * 512]);
            } else {
                const int r = (c - CA) * 16 + rIn;
                async16(&Bt[(size_t)(colBase + r) * K + k0 + cIn], &Bs[buf][(c - CA) * 512]);
            }
        }
    };

    const int nk = K >> 5;
    stage(0, 0);

    for (int i = 0; i < nk; ++i) {
        __syncthreads();
        if (i + 1 < nk) stage((i + 1) & 1, (i + 1) << 5);

        const int b = i & 1;
        half8 af[MT], bf[NT];
#pragma unroll
        for (int m = 0; m < MT; ++m)
            af[m] = *(const half8*)(&As[b][(wrow * WM + m * 16 + l15) * 32 + quad * 8]);
#pragma unroll
        for (int n = 0; n < NT; ++n)
            bf[n] = *(const half8*)(&Bs[b][(wcol * WN + n * 16 + l15) * 32 + quad * 8]);

#pragma unroll
        for (int m = 0; m < MT; ++m)
#pragma unroll
            for (int n = 0; n < NT; ++n)
                acc[m][n] = __builtin_amdgcn_mfma_f32_16x16x32_f16(
                    af[m], bf[n], acc[m][n], 0, 0, 0);
    }

#pragma unroll
    for (int m = 0; m < MT; ++m) {
#pragma unroll
        for (int n = 0; n < NT; ++n) {
            int col = colBase + wcol * WN + n * 16 + l15;
#pragma unroll
            for (int r = 0; r < 4; ++r) {
                int row = rowBase + wrow * WM + m * 16 + quad * 4 + r;
                C[sidx(row, col)] = (_Float16)acc[m][n][r];
            }
        }
    }
}

template <int TM, int TN>
__global__ __launch_bounds__(256) void gemm_f16_t(
    const _Float16* __restrict__ A,
    const _Float16* __restrict__ Bt,
    _Float16* __restrict__ C,
    int K, int Nc)
{
    gemm_body<TM, TN>(blockIdx.x, blockIdx.y, A, Bt, C, K, Nc);
}

// ---------------------------------------------------------------------------
// Dual-relu GEMM body (R15-proven): S_sliced = relu(Z)@Wtop + Z@Wbot.
// Bt=[Nc x 1024] (top half k<512, bottom k>=512), Z=[M_PAD x 512] row-major.
// ---------------------------------------------------------------------------
template <int TM, int TN>
__device__ __forceinline__ void gemm_dual(
    int bx, int by,
    const _Float16* __restrict__ Z,     // [M_PAD x 512]
    const _Float16* __restrict__ Bt,    // [Nc x 1024]
    _Float16* __restrict__ C,           // S sliced
    int Nc)
{
    constexpr int WM = TM / 2;
    constexpr int WN = TN / 2;
    constexpr int MT = WM / 16;
    constexpr int NT = WN / 16;
    constexpr int CA = TM / 16;
    constexpr int CB = TN / 16;
    constexpr int NCH = CA + 2 * CB;    // A + Btop + Bbot chunks

    __shared__ _Float16 As [2][TM * 32];
    __shared__ _Float16 Bs0[2][TN * 32];
    __shared__ _Float16 Bs1[2][TN * 32];

    const int t    = threadIdx.x;
    const int lane = t & 63;
    const int wid  = t >> 6;
    const int wrow = wid >> 1;
    const int wcol = wid & 1;
    const int quad = lane >> 4;
    const int l15  = lane & 15;

    const int rowBase = by * TM;
    const int colBase = bx * TN;

    const int rIn = lane >> 2;
    const int cIn = (lane & 3) * 8;

    f32x4 acc[MT][NT];
#pragma unroll
    for (int m = 0; m < MT; ++m)
#pragma unroll
        for (int n = 0; n < NT; ++n)
            acc[m][n] = (f32x4){0.f, 0.f, 0.f, 0.f};

    auto stage = [&](int buf, int k0) {
#pragma unroll
        for (int p = 0; p < NCH / 4; ++p) {
            const int c = wid + p * 4;
            if (c < CA) {
                const int r = c * 16 + rIn;
                async16(&Z[(size_t)(rowBase + r) * 512 + k0 + cIn], &As[buf][c * 512]);
            } else if (c < CA + CB) {
                const int cc = c - CA;
                const int r = cc * 16 + rIn;
                async16(&Bt[(size_t)(colBase + r) * 1024 + k0 + cIn], &Bs0[buf][cc * 512]);
            } else {
                const int cc = c - CA - CB;
                const int r = cc * 16 + rIn;
                async16(&Bt[(size_t)(colBase + r) * 1024 + 512 + k0 + cIn], &Bs1[buf][cc * 512]);
            }
        }
    };

    stage(0, 0);

    for (int i = 0; i < 16; ++i) {      // K=512 in steps of 32
        __syncthreads();
        if (i + 1 < 16) stage((i + 1) & 1, (i + 1) << 5);

        const int b = i & 1;
        half8 af[MT], ar[MT], bf0[NT], bf1[NT];
#pragma unroll
        for (int m = 0; m < MT; ++m) {
            af[m] = *(const half8*)(&As[b][(wrow * WM + m * 16 + l15) * 32 + quad * 8]);
#pragma unroll
            for (int j = 0; j < 8; ++j)
                ar[m][j] = af[m][j] > (_Float16)0 ? af[m][j] : (_Float16)0;
        }
#pragma unroll
        for (int n = 0; n < NT; ++n) {
            bf0[n] = *(const half8*)(&Bs0[b][(wcol * WN + n * 16 + l15) * 32 + quad * 8]);
            bf1[n] = *(const half8*)(&Bs1[b][(wcol * WN + n * 16 + l15) * 32 + quad * 8]);
        }

#pragma unroll
        for (int m = 0; m < MT; ++m)
#pragma unroll
            for (int n = 0; n < NT; ++n) {
                acc[m][n] = __builtin_amdgcn_mfma_f32_16x16x32_f16(
                    ar[m], bf0[n], acc[m][n], 0, 0, 0);
                acc[m][n] = __builtin_amdgcn_mfma_f32_16x16x32_f16(
                    af[m], bf1[n], acc[m][n], 0, 0, 0);
            }
    }

#pragma unroll
    for (int m = 0; m < MT; ++m) {
#pragma unroll
        for (int n = 0; n < NT; ++n) {
            int col = colBase + wcol * WN + n * 16 + l15;
#pragma unroll
            for (int r = 0; r < 4; ++r) {
                int row = rowBase + wrow * WM + m * 16 + quad * 4 + r;
                C[sidx(row, col)] = (_Float16)acc[m][n][r];
            }
        }
    }
}

template <int TM, int TN>
__global__ __launch_bounds__(256) void gemm_dual_k(
    const _Float16* __restrict__ Z,
    const _Float16* __restrict__ Bt,
    _Float16* __restrict__ C,
    int Nc)
{
    gemm_dual<TM, TN>(blockIdx.x, blockIdx.y, Z, Bt, C, Nc);
}

// ---------------------------------------------------------------------------
// prep + edge-scatter fused (R16-proven): scatter blocks first (latency-
// bound, hide under BW-bound converts); slot = atomicAdd(counts[row]) is
// the scatter address. ev entry PACKED: col(u16) | fp16(val)<<16 = 4B/edge.
// Then x fp32->fp16 and LDS-tiled W transposes.
// ---------------------------------------------------------------------------
#define SCAT_B    1250   // 320000 / 256
#define PREP_XB   5000
#define PREP_W0B  256    // 512x512  : 16x16 tiles of 32x32
#define PREP_W1B  512    // 1024x512 : 32x16
#define PREP_W2B  256    // 1024x256 : 32x8
#define PREPH_BLKS (SCAT_B + PREP_XB + PREP_W0B + PREP_W1B + PREP_W2B)

__device__ __forceinline__ void tile_tr(const float* __restrict__ W,
                                        _Float16* __restrict__ Wt,
                                        int K, int Nc, int tR, int tC, int t) {
    __shared__ float tile[32][33];
    const int ty = t >> 5, tx = t & 31;
#pragma unroll
    for (int it = 0; it < 4; ++it)
        tile[ty + 8 * it][tx] = W[(size_t)(tR * 32 + ty + 8 * it) * Nc + tC * 32 + tx];
    __syncthreads();
#pragma unroll
    for (int it = 0; it < 4; ++it)
        Wt[(size_t)(tC * 32 + ty + 8 * it) * K + tR * 32 + tx] =
            (_Float16)tile[tx][ty + 8 * it];
}

__global__ __launch_bounds__(256) void prep_scatter(
    const float* __restrict__ x,  _Float16* __restrict__ Xh,
    const float* __restrict__ W0, _Float16* __restrict__ W0t,
    const float* __restrict__ W1, _Float16* __restrict__ W1t,
    const float* __restrict__ W2, _Float16* __restrict__ W2t,
    const int* __restrict__ edge_row, const int* __restrict__ edge_col,
    const float* __restrict__ edge_val,
    int* __restrict__ counts, unsigned* __restrict__ ev) {
    const int t = threadIdx.x;
    int b = blockIdx.x;
    if (b < SCAT_B) {
        int i = b * 256 + t;
        if (i < N_EDGES) {
            int r = edge_row[i];
            int slot = atomicAdd(&counts[r], 1);
            if (slot < ROWCAP) { // OOB guard; never taken for Poisson(32)
                _Float16 hv = (_Float16)edge_val[i];
                unsigned short hb;
                __builtin_memcpy(&hb, &hv, 2);
                ev[(size_t)r * ROWCAP + slot] =
                    (unsigned)edge_col[i] | ((unsigned)hb << 16);
            }
        }
        return;
    }
    b -= SCAT_B;
    if (b < PREP_XB) {
        int i = b * 256 + t;                 // exactly 10000*512/4 threads
        f32x4 v = *(const f32x4*)(x + (size_t)i * 4);
        half4 h;
        h[0] = (_Float16)v[0]; h[1] = (_Float16)v[1];
        h[2] = (_Float16)v[2]; h[3] = (_Float16)v[3];
        *(half4*)(Xh + (size_t)i * 4) = h;
        return;
    }
    b -= PREP_XB;
    if (b < PREP_W0B) { tile_tr(W0, W0t, 512, 512, b >> 4, b & 15, t); return; }
    b -= PREP_W0B;
    if (b < PREP_W1B) { tile_tr(W1, W1t, 1024, 512, b >> 4, b & 15, t); return; }
    b -= PREP_W1B;
    { tile_tr(W2, W2t, 1024, 256, b >> 3, b & 7, t); }
}

// ---------------------------------------------------------------------------
// SpMM, feature-sliced, slice-major S + XCD-pinned slices (R17-exact grid
// and loop) with packed 4B ev. Working set per XCD pair = 2.59 MB S-slice
// + 3.84 MB ev = 6.4 MB < 8 MB L2 -> chain loads L2-resident.
// Per-lane accumulation order identical to R17.
// ---------------------------------------------------------------------------
template <int D, bool FINAL>
__global__ __launch_bounds__(256) void spmm_slice(
    const int* __restrict__ counts,
    const unsigned* __restrict__ ev,    // packed: col | fp16(val)<<16
    const _Float16* __restrict__ S,     // sliced: [D/128][M_PAD][128]
    const float* __restrict__ bias,     // [D]
    _Float16* __restrict__ Zout,        // [M_PAD x D] if !FINAL
    float* __restrict__ Fout)           // [N_NODES x D] if FINAL
{
    constexpr int NS  = D / 128;        // slices
    constexpr int XPS = 8 / NS;         // XCDs per slice
    const int bid = blockIdx.x;
    const int s   = (bid & 7) / XPS;                      // slice -> XCD group
    const int rq  = (bid >> 3) * XPS + (bid & (XPS - 1)); // row-quad
    const int w  = threadIdx.x >> 6;    // wave -> row within quad
    const int row = rq * 4 + w;
    const int lane = threadIdx.x & 63;
    const int g = lane >> 4;            // edge-group 0..3
    const int l = lane & 15;            // feature-lane

    const int r0 = row * ROWCAP;
    const int r1 = r0 + counts[row];

    float acc[8];
#pragma unroll
    for (int j = 0; j < 8; ++j) acc[j] = 0.f;

    const _Float16* __restrict__ Sb = S + (size_t)s * M_PAD * 128 + l * 8;

    int e = r0 + g;
    // unroll 4: per-group stride 4 -> quad stride 16; 4 gathers in flight
    for (; e + 12 < r1; e += 16) {
        unsigned p[4];
        half8  v[4];
#pragma unroll
        for (int u = 0; u < 4; ++u) p[u] = ev[e + 4 * u];
#pragma unroll
        for (int u = 0; u < 4; ++u)
            v[u] = *(const half8*)(Sb + (size_t)(p[u] & 0xFFFFu) * 128);
#pragma unroll
        for (int u = 0; u < 4; ++u) {
            const float pv = unpack_val(p[u]);
#pragma unroll
            for (int j = 0; j < 8; ++j) acc[j] += pv * (float)v[u][j];
        }
    }
    for (; e + 4 < r1; e += 8) {
        unsigned p0 = ev[e];
        unsigned p1 = ev[e + 4];
        half8 v0 = *(const half8*)(Sb + (size_t)(p0 & 0xFFFFu) * 128);
        half8 v1 = *(const half8*)(Sb + (size_t)(p1 & 0xFFFFu) * 128);
        const float w0 = unpack_val(p0);
        const float w1 = unpack_val(p1);
#pragma unroll
        for (int j = 0; j < 8; ++j) {
            acc[j] += w0 * (float)v0[j];
            acc[j] += w1 * (float)v1[j];
        }
    }
    if (e < r1) {
        unsigned p0 = ev[e];
        half8 v0 = *(const half8*)(Sb + (size_t)(p0 & 0xFFFFu) * 128);
        const float w0 = unpack_val(p0);
#pragma unroll
        for (int j = 0; j < 8; ++j) acc[j] += w0 * (float)v0[j];
    }

    // butterfly across the 4 edge-groups (lanes xor 16, xor 32)
#pragma unroll
    for (int j = 0; j < 8; ++j) {
        acc[j] += __shfl_xor(acc[j], 16, 64);
        acc[j] += __shfl_xor(acc[j], 32, 64);
    }

    const int f0 = s * 128 + l * 8;
    f32x4 b0 = *(const f32x4*)(bias + f0);
    f32x4 b1 = *(const f32x4*)(bias + f0 + 4);

    if constexpr (FINAL) {
        if (g == 0) {
            f32x4 o = {acc[0] + b0[0], acc[1] + b0[1], acc[2] + b0[2], acc[3] + b0[3]};
            *(f32x4*)(Fout + (size_t)row * D + f0) = o;
        } else if (g == 1) {
            f32x4 o = {acc[4] + b1[0], acc[5] + b1[1], acc[6] + b1[2], acc[7] + b1[3]};
            *(f32x4*)(Fout + (size_t)row * D + f0 + 4) = o;
        }
    } else {
        if (g == 0) {                   // single fp16 store of x_ (pre-relu)
            half8 h;
#pragma unroll
            for (int j = 0; j < 4; ++j) h[j] = (_Float16)(acc[j] + b0[j]);
#pragma unroll
            for (int j = 0; j < 4; ++j) h[4 + j] = (_Float16)(acc[4 + j] + b1[j]);
            *(half8*)(Zout + (size_t)row * D + f0) = h;
        }
    }
}

// ---------------------------------------------------------------------------
static inline char* alignp(char* p, size_t a) {
    return (char*)(((uintptr_t)p + a - 1) & ~(uintptr_t)(a - 1));
}

extern "C" void kernel_launch(void* const* d_in, const int* in_sizes, int n_in,
                              void* d_out, int out_size, void* d_ws, size_t ws_size,
                              hipStream_t stream) {
    const float* x        = (const float*)d_in[0];   // [10000 x 512]
    const int*   edge_row = (const int*)d_in[1];     // [E]
    const int*   edge_col = (const int*)d_in[2];     // [E]
    const float* edge_val = (const float*)d_in[3];   // [E]
    const float* W0 = (const float*)d_in[4];         // [512 x 512]
    const float* W1 = (const float*)d_in[5];         // [1024 x 512]
    const float* W2 = (const float*)d_in[6];         // [1024 x 256]
    const float* b0 = (const float*)d_in[7];
    const float* b1 = (const float*)d_in[8];
    const float* b2 = (const float*)d_in[9];
    float* out = (float*)d_out;                      // [10000 x 256]

    // ---- workspace carve-up ----
    char* p = (char*)d_ws;
    _Float16* Xh  = (_Float16*)alignp(p, 256);  p = (char*)(Xh  + (size_t)M_PAD * 512);
    _Float16* S   = (_Float16*)alignp(p, 256);  p = (char*)(S   + (size_t)M_PAD * 512);
    _Float16* Z   = (_Float16*)alignp(p, 256);  p = (char*)(Z   + (size_t)M_PAD * 512);
    _Float16* W0t = (_Float16*)alignp(p, 256);  p = (char*)(W0t + (size_t)512 * 512);
    _Float16* W1t = (_Float16*)alignp(p, 256);  p = (char*)(W1t + (size_t)512 * 1024);
    _Float16* W2t = (_Float16*)alignp(p, 256);  p = (char*)(W2t + (size_t)256 * 1024);
    int*      counts = (int*)alignp(p, 256);    p = (char*)(counts + N_NODES);
    unsigned* ev     = (unsigned*)alignp(p, 256); p = (char*)(ev + (size_t)N_NODES * ROWCAP);

    // ---- zero counts (graph memset node), then prep+scatter fused ----
    (void)hipMemsetAsync(counts, 0, N_NODES * sizeof(int), stream);
    prep_scatter<<<PREPH_BLKS, 256, 0, stream>>>(x, Xh, W0, W0t, W1, W1t, W2, W2t,
                                                 edge_row, edge_col, edge_val,
                                                 counts, ev);

    // ---- layer 0: GEMM (64x128) -> sliced S ----
    gemm_f16_t<64, 128><<<dim3(4, M_PAD / 64), 256, 0, stream>>>(Xh, W0t, S, 512, 512);
    spmm_slice<512, false><<<(N_NODES / 4) * 4, 256, 0, stream>>>(counts, ev, S, b0, Z, nullptr);
    // ---- layer 1: dual-relu GEMM on Z -> sliced S ----
    gemm_dual_k<64, 128><<<dim3(4, M_PAD / 64), 256, 0, stream>>>(Z, W1t, S, 512);
    spmm_slice<512, false><<<(N_NODES / 4) * 4, 256, 0, stream>>>(counts, ev, S, b1, Z, nullptr);
    // ---- layer 2: dual-relu GEMM, Nc=256 -> sliced S ----
    gemm_dual_k<64, 64><<<dim3(4, M_PAD / 64), 256, 0, stream>>>(Z, W2t, S, 256);
    spmm_slice<256, true><<<(N_NODES / 4) * 2, 256, 0, stream>>>(counts, ev, S, b2, nullptr, out);
}